// Round 1
// baseline (476.404 us; speedup 1.0000x reference)
//
#include <hip/hip_runtime.h>
#include <cmath>

#define T_LEN 60000
#define BATCH 4
#define NBANDS 8
#define FB 32
#define EPS 1e-8f

// ---------------- K0: zero the max-reduction slots (ws is poisoned 0xAA) ----
__global__ void k0_init(int* __restrict__ m) {
    if (threadIdx.x < 8) m[threadIdx.x] = 0;   // 0 bits == 0.0f; all maxed vals >= 0
}

// ---------------- K1: x -> xp  (log1p compress, 5-tap diff, relu, sum over 32 freqs)
// grid: (ceil(T/256), 8 bands, 4 batches), block 256
__global__ __launch_bounds__(256) void k1_xp(
        const float* __restrict__ x, const float* __restrict__ log_gamma,
        const float* __restrict__ diff_w, const float* __restrict__ diff_b,
        float* __restrict__ xp) {
    __shared__ float sh[260];
    const int tid = threadIdx.x;
    const int t0 = blockIdx.x * 256;
    const int band = blockIdx.y;
    const int b = blockIdx.z;
    const float gamma = __expf(log_gamma[band]);
    float dw[5];
#pragma unroll
    for (int k = 0; k < 5; ++k) dw[k] = diff_w[band * 5 + k];
    const float db = diff_b[band];
    const size_t row0 = ((size_t)(b * 256 + band * 32)) * T_LEN;
    float acc = 0.f;
    for (int f = 0; f < 32; ++f) {
        const float* row = x + row0 + (size_t)f * T_LEN;
        __syncthreads();  // protect sh from previous iteration's readers
        for (int i = tid; i < 260; i += 256) {
            int tt = t0 + i - 2;
            float v = 0.f;  // conv zero-pads xl; log1p(0)==0 anyway
            if (tt >= 0 && tt < T_LEN) v = __logf(fmaf(gamma, row[tt], 1.0f));
            sh[i] = v;
        }
        __syncthreads();
        float xd = db;
#pragma unroll
        for (int k = 0; k < 5; ++k) xd = fmaf(dw[k], sh[tid + k], xd);
        acc += fmaxf(xd, 0.f);
    }
    const int t = t0 + tid;
    if (t < T_LEN) xp[((size_t)(b * NBANDS + band)) * T_LEN + t] = acc;
}

// ---------------- K2: xp -> xg  (local-avg subtract 11-tap, band mix, gaussian 15-tap, relu)
// + per-batch atomic max of xg. grid: (ceil(T/256), 4), block 256
__global__ __launch_bounds__(256) void k2_xg(
        const float* __restrict__ xp,
        const float* __restrict__ la_w, const float* __restrict__ la_b,
        const float* __restrict__ mix_w, const float* __restrict__ g_w,
        const float* __restrict__ g_b,
        float* __restrict__ xg, int* __restrict__ m1_bits) {
    __shared__ float shxp[NBANDS][280];
    __shared__ float shxm[272];
    __shared__ float red[4];
    const int tid = threadIdx.x;
    const int t0 = blockIdx.x * 256;
    const int b = blockIdx.y;
    for (int c = 0; c < NBANDS; ++c) {
        const float* row = xp + ((size_t)(b * NBANDS + c)) * T_LEN;
        for (int i = tid; i < 280; i += 256) {
            int tt = t0 + i - 12;
            shxp[c][i] = (tt >= 0 && tt < T_LEN) ? row[tt] : 0.f;  // zero-pad xp
        }
    }
    __syncthreads();
    // xm[t'] for t' in [t0-7, t0+263)  (j = t' - (t0-7))
    for (int j = tid; j < 270; j += 256) {
        int tp = t0 - 7 + j;
        float xm = 0.f;  // xm zero-padded outside [0,T)
        if (tp >= 0 && tp < T_LEN) {
            for (int c = 0; c < NBANDS; ++c) {
                float conv = la_b[c];
#pragma unroll
                for (int k = 0; k < 11; ++k)
                    conv = fmaf(la_w[c * 11 + k], shxp[c][j + k], conv);
                xm = fmaf(mix_w[c], shxp[c][j + 5] - conv, xm);
            }
        }
        shxm[j] = xm;
    }
    __syncthreads();
    const int t = t0 + tid;
    float v = g_b[0];
#pragma unroll
    for (int k = 0; k < 15; ++k) v = fmaf(g_w[k], shxm[tid + k], v);
    v = fmaxf(v, 0.f);
    if (t < T_LEN) xg[(size_t)b * T_LEN + t] = v;
    else v = 0.f;
    // block max reduce (v >= 0, so int compare == float compare, 0-init safe)
#pragma unroll
    for (int off = 32; off > 0; off >>= 1) v = fmaxf(v, __shfl_down(v, off));
    if ((tid & 63) == 0) red[tid >> 6] = v;
    __syncthreads();
    if (tid == 0) {
        float m = fmaxf(fmaxf(red[0], red[1]), fmaxf(red[2], red[3]));
        atomicMax(&m1_bits[b], __float_as_int(m));
    }
}

// ---------------- K3a: xg -> spectral_flux out, fa (sigmoid of fuser conv), max(fa)
// grid: (ceil(T/256), 4), block 256
__global__ __launch_bounds__(256) void k3a(
        const float* __restrict__ xg, const int* __restrict__ m1_bits,
        const float* __restrict__ fc_w, const float* __restrict__ fc_b,
        const float* __restrict__ fg_w, const float* __restrict__ fg_b,
        float* __restrict__ sf_out, float* __restrict__ fa_out,
        int* __restrict__ m2_bits) {
    __shared__ float shfm[272];
    __shared__ float red[4];
    const int tid = threadIdx.x;
    const int t0 = blockIdx.x * 256;
    const int b = blockIdx.y;
    const float inv = 1.f / (__int_as_float(m1_bits[b]) + EPS);
    const float sfc = fc_w[0] + fc_w[1] + fc_w[2] + fc_w[3];
    const float fcb = fc_b[0];
    for (int i = tid; i < 270; i += 256) {
        int tt = t0 + i - 7;
        float v = 0.f;  // fm zero-padded outside [0,T)
        if (tt >= 0 && tt < T_LEN)
            v = fmaf(sfc, xg[(size_t)b * T_LEN + tt] * inv, fcb);
        shfm[i] = v;
    }
    __syncthreads();
    const int t = t0 + tid;
    float fs = fg_b[0];
#pragma unroll
    for (int k = 0; k < 15; ++k) fs = fmaf(fg_w[k], shfm[tid + k], fs);
    float sig = 1.f / (1.f + __expf(-fs));
    float v;
    if (t < T_LEN) {
        sf_out[(size_t)b * T_LEN + t] = xg[(size_t)b * T_LEN + t] * inv;
        fa_out[(size_t)b * T_LEN + t] = sig;
        v = sig;
    } else {
        v = 0.f;
    }
#pragma unroll
    for (int off = 32; off > 0; off >>= 1) v = fmaxf(v, __shfl_down(v, off));
    if ((tid & 63) == 0) red[tid >> 6] = v;
    __syncthreads();
    if (tid == 0) {
        float m = fmaxf(fmaxf(red[0], red[1]), fmaxf(red[2], red[3]));
        atomicMax(&m2_bits[b], __float_as_int(m));
    }
}

// ---------------- K3b: fused_nov = fa / (m2 + eps), in-place on d_out 2nd half
__global__ void k3b(float* __restrict__ fa, const int* __restrict__ m2_bits) {
    int idx = blockIdx.x * 256 + threadIdx.x;
    if (idx >= BATCH * T_LEN) return;
    int b = idx / T_LEN;
    float inv = 1.f / (__int_as_float(m2_bits[b]) + EPS);
    fa[idx] = fa[idx] * inv;
}

extern "C" void kernel_launch(void* const* d_in, const int* in_sizes, int n_in,
                              void* d_out, int out_size, void* d_ws, size_t ws_size,
                              hipStream_t stream) {
    const float* x    = (const float*)d_in[0];
    const float* lg   = (const float*)d_in[1];
    const float* dw   = (const float*)d_in[2];
    const float* db   = (const float*)d_in[3];
    const float* law  = (const float*)d_in[4];
    const float* lab  = (const float*)d_in[5];
    const float* mixw = (const float*)d_in[6];
    const float* gw   = (const float*)d_in[7];
    const float* gb   = (const float*)d_in[8];
    const float* fcw  = (const float*)d_in[9];
    const float* fcb  = (const float*)d_in[10];
    const float* fgw  = (const float*)d_in[11];
    const float* fgb  = (const float*)d_in[12];

    float* ws = (float*)d_ws;
    float* xp = ws;                                   // 4*8*60000 = 1,920,000 f
    float* xg = ws + (size_t)BATCH * NBANDS * T_LEN;  // 240,000 f
    int*   m1 = (int*)(xg + (size_t)BATCH * T_LEN);   // 4 ints
    int*   m2 = m1 + 4;                               // 4 ints

    float* sf_out = (float*)d_out;                    // [4,60000]
    float* fn_out = sf_out + (size_t)BATCH * T_LEN;   // [4,60000] (fa in-place)

    const int tb = (T_LEN + 255) / 256;

    k0_init<<<dim3(1), dim3(64), 0, stream>>>(m1);
    k1_xp<<<dim3(tb, NBANDS, BATCH), dim3(256), 0, stream>>>(x, lg, dw, db, xp);
    k2_xg<<<dim3(tb, BATCH), dim3(256), 0, stream>>>(xp, law, lab, mixw, gw, gb, xg, m1);
    k3a<<<dim3(tb, BATCH), dim3(256), 0, stream>>>(xg, m1, fcw, fcb, fgw, fgb,
                                                   sf_out, fn_out, m2);
    k3b<<<dim3((BATCH * T_LEN + 255) / 256), dim3(256), 0, stream>>>(fn_out, m2);
}